// Round 1
// baseline (456.573 us; speedup 1.0000x reference)
//
#include <hip/hip_runtime.h>

typedef __attribute__((ext_vector_type(4))) float f32x4;
typedef __attribute__((ext_vector_type(8))) short bf16x8;

__device__ __forceinline__ short f2bf(float f) {
  union { float f; unsigned u; } x; x.f = f;
  return (short)((x.u + 0x7fffu + ((x.u >> 16) & 1u)) >> 16);   // RNE truncate to bf16
}

// ---------------- prep: weights->bf16, q padded->bf16, bias table expand ----
__global__ __launch_bounds__(256) void prep_kernel(
    const float* __restrict__ qkv_w, const float* __restrict__ proj_w,
    const float* __restrict__ qg, const float* __restrict__ table,
    short* __restrict__ wq_b, short* __restrict__ wp_b,
    short* __restrict__ q_b, float* __restrict__ biasg)
{
  int idx = blockIdx.x * 256 + threadIdx.x;
  if (idx < 131072) { wq_b[idx] = f2bf(qkv_w[idx]); return; }
  idx -= 131072;
  if (idx < 65536) { wp_b[idx] = f2bf(proj_w[idx]); return; }
  idx -= 65536;
  if (idx < 1048576) {                       // q padded: [64 win][8 h][64 n][32 d]
    int d = idx & 31, n = (idx >> 5) & 63, hh = (idx >> 11) & 7, w = idx >> 14;
    float v = (n < 49) ? qg[((w * 8 + hh) * 49 + n) * 32 + d] : 0.f;
    q_b[idx] = f2bf(v);
    return;
  }
  idx -= 1048576;
  if (idx < 19208) {                         // bias: [8 h][49 q][49 k]
    int hh = idx / 2401, rem = idx % 2401;
    int n = rem / 49, n2 = rem % 49;
    int di = n / 7 - n2 / 7 + 6, dj = n % 7 - n2 % 7 + 6;
    biasg[idx] = table[(di * 13 + dj) * 8 + hh];
  }
}

// ---------------- fused per-window kernel: kv-GEMM + attn + proj ------------
// block = 1 window (49 tokens), 512 threads = 8 waves, wave w == head w.
__global__ __launch_bounds__(512) void fused_win(
    const float* __restrict__ x, const short* __restrict__ q_b,
    const short* __restrict__ wq_b, const short* __restrict__ wp_b,
    const float* __restrict__ qkv_b, const float* __restrict__ proj_b,
    const float* __restrict__ biasg, float* __restrict__ out)
{
  __shared__ __align__(16) char smem[98304];          // 96 KiB
  short* As = (short*)smem;                           // [64][256] bf16 x-tile (swz)
  short* Kl = (short*)(smem + 32768);                 // [64][256] bf16 K (swz)
  short* Pl = (short*)smem;                           // [8][64][64] bf16 P (aliases As+Kl)
  short* vT = (short*)(smem + 65536);                 // [256][64] bf16 V^T (swz)
  short* Ol = (short*)(smem + 65536);                 // [64][256] bf16 attn-out (aliases vT)

  const int tid = threadIdx.x;
  const int b   = blockIdx.x;
  const int lane = tid & 63;
  const int w   = tid >> 6;        // wave id == head id
  const int lr  = lane & 15;       // frag row/col (lane&15)
  const int lg  = lane >> 4;       // k-group

  // -- phase 0: stage x[b] fp32->bf16 into As, rows 49..63 zeroed -----------
  {
    const float* xsrc = x + (long)b * 49 * 256;
    #pragma unroll
    for (int it = 0; it < 4; ++it) {
      int idx = it * 512 + tid;
      int row = idx >> 5, s = idx & 31;       // 16B slot s of row
      bf16x8 v;
      if (row < 49) {
        const float4* p = (const float4*)(xsrc + row * 256 + s * 8);
        float4 f0 = p[0], f1 = p[1];
        v[0] = f2bf(f0.x); v[1] = f2bf(f0.y); v[2] = f2bf(f0.z); v[3] = f2bf(f0.w);
        v[4] = f2bf(f1.x); v[5] = f2bf(f1.y); v[6] = f2bf(f1.z); v[7] = f2bf(f1.w);
      } else {
        #pragma unroll
        for (int j = 0; j < 8; ++j) v[j] = 0;
      }
      *(bf16x8*)(&As[row * 256 + ((s ^ (row & 7)) << 3)]) = v;
    }
  }
  __syncthreads();

  // -- phase 1: kv = x @ qkv_w^T  (wave w -> output cols [64w,64w+64)) ------
  f32x4 acc[4][4] = {};
  {
    const short* Bb = wq_b + (w * 64 + lr) * 256 + lg * 8;
    #pragma unroll 2
    for (int kk = 0; kk < 8; ++kk) {
      bf16x8 a[4], bfr[4];
      #pragma unroll
      for (int mt = 0; mt < 4; ++mt) {
        int row = mt * 16 + lr;
        a[mt] = *(const bf16x8*)(&As[row * 256 + (((kk * 4 + lg) ^ (row & 7)) << 3)]);
      }
      #pragma unroll
      for (int nt = 0; nt < 4; ++nt)
        bfr[nt] = *(const bf16x8*)(Bb + nt * 16 * 256 + kk * 32);
      #pragma unroll
      for (int mt = 0; mt < 4; ++mt)
        #pragma unroll
        for (int nt = 0; nt < 4; ++nt)
          acc[mt][nt] = __builtin_amdgcn_mfma_f32_16x16x32_bf16(a[mt], bfr[nt], acc[mt][nt], 0, 0, 0);
    }
  }
  // epilogue: +qkv_b; waves 0-3 write K rows, waves 4-7 write V transposed
  #pragma unroll
  for (int nt = 0; nt < 4; ++nt) {
    int c = w * 64 + nt * 16 + lr;
    float bv = qkv_b[c];
    #pragma unroll
    for (int mt = 0; mt < 4; ++mt)
      #pragma unroll
      for (int r = 0; r < 4; ++r) {
        int row = mt * 16 + lg * 4 + r;       // D layout: row=(lane>>4)*4+r (+16mt)
        short val = f2bf(acc[mt][nt][r] + bv);
        if (w < 4) {
          Kl[row * 256 + (((c >> 3) ^ (row & 7)) << 3) + (c & 7)] = val;
        } else {
          int d = c - 256;
          vT[d * 64 + (((row >> 3) ^ (d & 7)) << 3) + (row & 7)] = val;
        }
      }
  }
  __syncthreads();

  // -- phase 2: S = q @ K^T  (one MFMA K-step: hd==32) ----------------------
  f32x4 s[4][4] = {};
  {
    const short* qsrc = q_b + (((long)(b >> 6) * 8 + w) * 64) * 32 + lg * 8;
    bf16x8 qa[4], kb[4];
    #pragma unroll
    for (int mt = 0; mt < 4; ++mt)
      qa[mt] = *(const bf16x8*)(qsrc + (mt * 16 + lr) * 32);
    #pragma unroll
    for (int nt = 0; nt < 4; ++nt) {
      int n = nt * 16 + lr;
      kb[nt] = *(const bf16x8*)(&Kl[n * 256 + (((w * 4 + lg) ^ (n & 7)) << 3)]);
    }
    #pragma unroll
    for (int mt = 0; mt < 4; ++mt)
      #pragma unroll
      for (int nt = 0; nt < 4; ++nt)
        s[mt][nt] = __builtin_amdgcn_mfma_f32_16x16x32_bf16(qa[mt], kb[nt], s[mt][nt], 0, 0, 0);
  }
  __syncthreads();   // all Kl reads done before P aliases it

  // -- phase 3: softmax(S*scale + bias), P -> LDS (bf16, swizzled) ----------
  float rinv[4][4];
  {
    const float* bh = biasg + w * 2401;
    const float sc = 0.17677669529663687f;   // 32^-0.5
    #pragma unroll
    for (int mt = 0; mt < 4; ++mt) {
      #pragma unroll
      for (int r = 0; r < 4; ++r) {
        int row = mt * 16 + lg * 4 + r;
        float v0[4];
        #pragma unroll
        for (int nt = 0; nt < 4; ++nt) {
          int col = nt * 16 + lr;
          float t = s[mt][nt][r] * sc;
          if (col >= 49) t = -1e30f;          // mask pad keys -> exp==0 exactly
          else if (row < 49) t += bh[row * 49 + col];
          v0[nt] = t;
        }
        float mx = fmaxf(fmaxf(v0[0], v0[1]), fmaxf(v0[2], v0[3]));
        mx = fmaxf(mx, __shfl_xor(mx, 1));
        mx = fmaxf(mx, __shfl_xor(mx, 2));
        mx = fmaxf(mx, __shfl_xor(mx, 4));
        mx = fmaxf(mx, __shfl_xor(mx, 8));    // row lives in a 16-lane group
        float sum = 0.f;
        #pragma unroll
        for (int nt = 0; nt < 4; ++nt) { v0[nt] = __expf(v0[nt] - mx); sum += v0[nt]; }
        sum += __shfl_xor(sum, 1);
        sum += __shfl_xor(sum, 2);
        sum += __shfl_xor(sum, 4);
        sum += __shfl_xor(sum, 8);
        rinv[mt][r] = 1.f / sum;
        short* pr = &Pl[w * 4096 + row * 64];
        #pragma unroll
        for (int nt = 0; nt < 4; ++nt) {
          int col = nt * 16 + lr;
          pr[(((col >> 3) ^ (row & 7)) << 3) + (col & 7)] = f2bf(v0[nt]);
        }
      }
    }
  }
  __syncthreads();

  // -- phase 4: O = P @ V  (B-frags are contiguous reads of V^T) ------------
  f32x4 o[4][2] = {};
  {
    const short* ph = &Pl[w * 4096];
    #pragma unroll
    for (int ks = 0; ks < 2; ++ks) {
      bf16x8 pa[4], vb[2];
      #pragma unroll
      for (int mt = 0; mt < 4; ++mt) {
        int row = mt * 16 + lr;
        pa[mt] = *(const bf16x8*)(ph + row * 64 + (((ks * 4 + lg) ^ (row & 7)) << 3));
      }
      #pragma unroll
      for (int nt = 0; nt < 2; ++nt) {
        int d = w * 32 + nt * 16 + lr;
        vb[nt] = *(const bf16x8*)(&vT[d * 64 + (((ks * 4 + lg) ^ (d & 7)) << 3)]);
      }
      #pragma unroll
      for (int mt = 0; mt < 4; ++mt)
        #pragma unroll
        for (int nt = 0; nt < 2; ++nt)
          o[mt][nt] = __builtin_amdgcn_mfma_f32_16x16x32_bf16(pa[mt], vb[nt], o[mt][nt], 0, 0, 0);
    }
  }
  __syncthreads();   // all vT reads done before Ol aliases it

  // -- phase 5: O/l -> LDS [64][256] bf16 (swizzled) ------------------------
  #pragma unroll
  for (int mt = 0; mt < 4; ++mt)
    #pragma unroll
    for (int r = 0; r < 4; ++r) {
      int row = mt * 16 + lg * 4 + r;
      #pragma unroll
      for (int nt = 0; nt < 2; ++nt) {
        int col = w * 32 + nt * 16 + lr;
        Ol[row * 256 + (((col >> 3) ^ (row & 7)) << 3) + (col & 7)] =
            f2bf(o[mt][nt][r] * rinv[mt][r]);
      }
    }
  __syncthreads();

  // -- phase 6: out = O @ proj_w^T + proj_b  (wave w -> cols [32w,32w+32)) --
  f32x4 po[4][2] = {};
  {
    const short* Bb = wp_b + (w * 32 + lr) * 256 + lg * 8;
    #pragma unroll 2
    for (int kk = 0; kk < 8; ++kk) {
      bf16x8 a[4], bfr[2];
      #pragma unroll
      for (int mt = 0; mt < 4; ++mt) {
        int row = mt * 16 + lr;
        a[mt] = *(const bf16x8*)(&Ol[row * 256 + (((kk * 4 + lg) ^ (row & 7)) << 3)]);
      }
      #pragma unroll
      for (int nt = 0; nt < 2; ++nt)
        bfr[nt] = *(const bf16x8*)(Bb + nt * 16 * 256 + kk * 32);
      #pragma unroll
      for (int mt = 0; mt < 4; ++mt)
        #pragma unroll
        for (int nt = 0; nt < 2; ++nt)
          po[mt][nt] = __builtin_amdgcn_mfma_f32_16x16x32_bf16(a[mt], bfr[nt], po[mt][nt], 0, 0, 0);
    }
  }
  float* od = out + (long)b * 49 * 256;
  #pragma unroll
  for (int nt = 0; nt < 2; ++nt) {
    int co = w * 32 + nt * 16 + lr;
    float pb = proj_b[co];
    #pragma unroll
    for (int mt = 0; mt < 4; ++mt)
      #pragma unroll
      for (int r = 0; r < 4; ++r) {
        int row = mt * 16 + lg * 4 + r;
        if (row < 49) od[row * 256 + co] = po[mt][nt][r] + pb;
      }
  }
}

extern "C" void kernel_launch(void* const* d_in, const int* in_sizes, int n_in,
                              void* d_out, int out_size, void* d_ws, size_t ws_size,
                              hipStream_t stream) {
  const float* x      = (const float*)d_in[0];
  const float* qg     = (const float*)d_in[1];
  const float* qkv_w  = (const float*)d_in[2];
  const float* qkv_b  = (const float*)d_in[3];
  const float* proj_w = (const float*)d_in[4];
  const float* proj_b = (const float*)d_in[5];
  const float* table  = (const float*)d_in[6];
  float* out = (float*)d_out;

  char* ws = (char*)d_ws;                 // total scratch: ~2.45 MB
  short* wq_b  = (short*)ws;              // 262144 B  bf16 qkv_w [512][256]
  short* wp_b  = (short*)(ws + 262144);   // 131072 B  bf16 proj_w [256][256]
  short* q_b   = (short*)(ws + 393216);   // 2097152 B bf16 q padded [64][8][64][32]
  float* biasg = (float*)(ws + 2490368);  // 76832 B   f32 bias [8][49][49]

  const int prep_total = 131072 + 65536 + 1048576 + 19208;
  prep_kernel<<<(prep_total + 255) / 256, 256, 0, stream>>>(
      qkv_w, proj_w, qg, table, wq_b, wp_b, q_b, biasg);
  fused_win<<<4096, 512, 0, stream>>>(x, q_b, wq_b, wp_b, qkv_b, proj_b, biasg, out);
}